// Round 12
// baseline (317.295 us; speedup 1.0000x reference)
//
#include <hip/hip_runtime.h>

// log-ODE Neural CDE. B=32 chains, 32 windows, Heun = 2 vector-field evals
// per window. fp32 in/out, f32 accum, f16 weights/activations.
// 512 threads/block (8 waves), one block per batch element.
//
// R21 = R20 structure + W1/W2 moved from registers to LDS (read per-use).
// Post-mortem R20: accumulator revert did NOT clear the spill (VGPR 128,
// WRITE 713KB unchanged); spill = set-once weight words overflowing the
// 128 cap (WRITE pattern: ~44B/thread written once, reloads L2-absorbed).
// Registers are the binding constraint; LDS is 72% idle. So:
//  * Stage W1 (128x64) / W2 (128x128) as f16 into padded LDS (strides 72 /
//    136 f16 for bank spread) once at init. +53KB LDS -> ~72KB (1 block/CU).
//  * A reads its quarter (2 b128); B/P/E read A-frags (1 b128/MFMA) from
//    LDS. Frees w1A+w1f+w2f = 32 persistent regs. w3e/w3o stay in regs
//    (latency-critical dot2 chains in C/F).
//  * Everything else byte-identical to R20 (6 barriers/eval).
#define NBATCH 32
#define LPATH  513
#define NWIN   32
#define LSIG   36
#define DSTR   136   // [dir] stride sD1/sD2 (f16) = 17 uint4
#define USTR   72    // [dir] stride sU (f16) = 9 uint4
#define W1STR  72    // sW1h row stride (f16): 64 cols + 8 pad
#define W2STR  136   // sW2h row stride (f16): 128 cols + 8 pad

typedef unsigned int u32;
typedef _Float16 h2 __attribute__((ext_vector_type(2)));
typedef _Float16 f16x8 __attribute__((ext_vector_type(8)));
typedef float f32x4 __attribute__((ext_vector_type(4)));

__device__ __forceinline__ u32 pkh(float a, float b){
  return __builtin_bit_cast(u32, __builtin_amdgcn_cvt_pkrtz(a, b));
}
__device__ __forceinline__ float dot2(u32 a, u32 b, float c){
#if __has_builtin(__builtin_amdgcn_fdot2)
  return __builtin_amdgcn_fdot2(__builtin_bit_cast(h2,a),
                                __builtin_bit_cast(h2,b), c, false);
#else
  h2 x = __builtin_bit_cast(h2,a), y = __builtin_bit_cast(h2,b);
  return c + (float)x[0]*(float)y[0] + (float)x[1]*(float)y[1];
#endif
}
__device__ __forceinline__ float tanh_fast(float x){
  float e = __expf(2.f*x);
  return 1.f - 2.f/(e+1.f);
}

// DPP cross-lane adds: VALU-only, no LDS-pipe traffic.
#define DPP_XOR1 0xB1   // quad_perm [1,0,3,2]
#define DPP_XOR2 0x4E   // quad_perm [2,3,0,1]
#define DPP_ROR8 0x128  // row_ror:8 == lane^8 within each 16-lane row
#define DPP_HMIR 0x141  // row_half_mirror == lane^7 within each 8-lane half
template<int CTRL>
__device__ __forceinline__ float dppadd(float x){
  int v = __builtin_amdgcn_update_dpp(0, __builtin_bit_cast(int,x),
                                      CTRL, 0xF, 0xF, false);
  return x + __builtin_bit_cast(float, v);
}

extern "C" __global__ __launch_bounds__(512, 1)
void cde_kernel(const float* __restrict__ cv,
                const float* __restrict__ Wi1g, const float* __restrict__ bi1g,
                const float* __restrict__ Wi2g, const float* __restrict__ bi2g,
                const float* __restrict__ W1g,  const float* __restrict__ b1g,
                const float* __restrict__ W2g,  const float* __restrict__ b2g,
                const float* __restrict__ W3g,  const float* __restrict__ b3g,
                const float* __restrict__ Wrg,  const float* __restrict__ brg,
                const float* __restrict__ shg,
                float* __restrict__ outp)
{
  // ---- LDS (~72 KB) ----
  __shared__ __align__(16) float sG[NWIN*LSIG];
  __shared__ __align__(16) float sWr[256];
  __shared__ float sBr[4], sSh[1];
  __shared__ __align__(16) float sY[64];
  __shared__ float sK1[64], sLw[64];
  __shared__ __align__(16) float sC[64];       // C[j][i] per window
  __shared__ float sB2[128];                   // b2 (B-MFMA rows != t-row)
  __shared__ float sDp1[128], sDp2[128];       // lipswish derivs (A->P, B->E)
  __shared__ __align__(16) _Float16 sYinp[64];
  __shared__ __align__(16) _Float16 sH1[128];
  __shared__ __align__(16) _Float16 sH2[128];
  __shared__ __align__(16) _Float16 sFt[64*8];     // f transposed: [a][i]
  __shared__ __align__(16) _Float16 sU [16*USTR];  // u[j][a], dirs 8-15 zero
  __shared__ __align__(16) _Float16 sD1[16*DSTR];  // dirs 8-15 zero-padded
  __shared__ __align__(16) _Float16 sD2[8*DSTR];
  __shared__ __align__(16) _Float16 sW1h[128*W1STR];  // W1 f16, padded rows
  __shared__ __align__(16) _Float16 sW2h[128*W2STR];  // W2 f16, padded rows

  const int t  = threadIdx.x;        // 0..511
  const int b  = blockIdx.x;
  const int wv = t >> 6;             // wave id 0..7 (MFMA M-tile)
  const int l  = t & 63;             // lane id
  const int cn = l & 15;             // MFMA N-lane (col)
  const int kg = l >> 4;             // MFMA K-group
  const int r  = t >> 2;             // 0..127 (A row)
  const int m  = t & 1;              // A quarter bit 0
  const int g  = (t >> 1) & 1;       // A quarter bit 1
  const int i8 = t & 7;              // dir (C/F row-block; U-fold j)
  const int a8 = t >> 3;             // 0..63 (C/F col; U-fold elem)
  const int p  = i8*64 + a8;         // owned W3 row
  const int pE = i8*64 + (a8 & ~1);  // C/F pair's even row
  const int pO = i8*64 + (a8 |  1);  // C/F pair's odd row

  // ---- init consts + stage W1/W2 to LDS + zero-pad sU/sD1 dirs 8-15 ----
  if (t < 256) sWr[t] = Wrg[t];
  if (t < 4)   sBr[t] = brg[t];
  if (t == 0)  sSh[0] = shg[0];
  if (t < 128) sB2[t] = b2g[t];
  for (int z = t; z < 8*DSTR; z += 512) sD1[8*DSTR + z] = (_Float16)0.f;
  for (int z = t; z < 8*USTR; z += 512) sU[8*USTR + z] = (_Float16)0.f;
  {
    u32* w1s = (u32*)sW1h;
    const float2* W1f2 = (const float2*)W1g;
    for (int idx = t; idx < 128*32; idx += 512){       // 32 float2 per row
      int row = idx >> 5, cp = idx & 31;
      float2 v = W1f2[idx];
      w1s[row*(W1STR/2) + cp] = pkh(v.x, v.y);
    }
    u32* w2s = (u32*)sW2h;
    const float2* W2f2 = (const float2*)W2g;
    for (int idx = t; idx < 128*64; idx += 512){       // 64 float2 per row
      int row = idx >> 6, cp = idx & 63;
      float2 v = W2f2[idx];
      w2s[row*(W2STR/2) + cp] = pkh(v.x, v.y);
    }
  }

  // ---- depth-2 Lyndon log-signatures, one window per thread (t<32) ----
  if (t < NWIN){
    const float4* cv4 = (const float4*)cv;
    const int base = (b*LPATH + t*16)*2;
    float cur[8], pre[8], acc[8], lvw[28];
    { float4 a = cv4[base], d = cv4[base+1];
      cur[0]=a.x;cur[1]=a.y;cur[2]=a.z;cur[3]=a.w;
      cur[4]=d.x;cur[5]=d.y;cur[6]=d.z;cur[7]=d.w; }
    #pragma unroll
    for (int d=0; d<8; d++){ pre[d]=0.f; acc[d]=0.f; }
    #pragma unroll
    for (int pq=0; pq<28; pq++) lvw[pq]=0.f;
    for (int w=1; w<=16; w++){
      float nxt[8], inc[8];
      { float4 a = cv4[base+2*w], d = cv4[base+2*w+1];
        nxt[0]=a.x;nxt[1]=a.y;nxt[2]=a.z;nxt[3]=a.w;
        nxt[4]=d.x;nxt[5]=d.y;nxt[6]=d.z;nxt[7]=d.w; }
      #pragma unroll
      for (int d=0; d<8; d++) inc[d] = nxt[d]-cur[d];
      int pq=0;
      #pragma unroll
      for (int i=0; i<8; i++)
        #pragma unroll
        for (int j2=i+1; j2<8; j2++){ lvw[pq] += pre[i]*inc[j2] - pre[j2]*inc[i]; pq++; }
      #pragma unroll
      for (int d=0; d<8; d++){ acc[d]+=inc[d]; pre[d]+=inc[d]; cur[d]=nxt[d]; }
    }
    float* gd = &sG[t*LSIG];
    #pragma unroll
    for (int d=0; d<8; d++) gd[d] = acc[d];
    #pragma unroll
    for (int pq=0; pq<28; pq++) gd[8+pq] = 0.5f*lvw[pq];
  }

  // ---- y0 = Wi2 @ lipswish(Wi1 @ x0 + bi1) + bi2 ----
  if (t < 64){
    float z = bi1g[t];
    #pragma unroll
    for (int d=0; d<8; d++) z += Wi1g[t*8+d] * cv[(b*LPATH)*8 + d];
    float s = 1.f/(1.f+__expf(-z));
    sLw[t] = 0.909f*z*s;
  }
  __syncthreads();
  if (t < 64){
    float z = bi2g[t];
    #pragma unroll 8
    for (int k=0; k<64; k++) z += Wi2g[t*64+k] * sLw[k];
    sY[t] = z;
    sYinp[t] = (_Float16)z;
  }
  __syncthreads();
  if (t < 4){
    float z = sBr[t] + sSh[0];
    #pragma unroll 8
    for (int a=0; a<64; a++) z += sWr[t*64+a]*sY[a];
    outp[(b*33 + 0)*4 + t] = z;
  }

  // ---- per-thread weight registers (ONLY W3 halves; W1/W2 live in LDS) ----
  // w3e/w3o: K-half (a8&1) of rows pE/pO -> C and F (dot2).
  u32 w3e[32], w3o[32];
  {
    const float4* W3f4 = (const float4*)W3g;
    #pragma unroll
    for (int k=0; k<16; k++){
      float4 v = W3f4[pE*32 + (a8&1)*16 + k];
      w3e[2*k]   = pkh(v.x, v.y);
      w3e[2*k+1] = pkh(v.z, v.w);
    }
    #pragma unroll
    for (int k=0; k<16; k++){
      float4 v = W3f4[pO*32 + (a8&1)*16 + k];
      w3o[2*k]   = pkh(v.x, v.y);
      w3o[2*k+1] = pkh(v.z, v.w);
    }
  }
  const float b1r = b1g[r], b3r = b3g[p];

  float gi = 0.f;       // gcur[i8], per window

  // One vector-field eval. mode 0: k1 (sK1, sYinp=y+k1, fused readout in A).
  // mode 1: k2 (Heun update fused in F).
  auto EVAL = [&](int mode, int s){
    __syncthreads();                          // sYinp (and sY, sC) ready
    float fr;
    // ---- A: h1 = lipswish(W1 y + b1); (m,g) quarter, weights from LDS ----
    {
      if (mode == 0 && s > 0 && t >= 504 && t < 508){
        int o = t - 504;
        float z = sBr[o] + sSh[0];
        const float4* wr4 = (const float4*)&sWr[o*64];
        const float4* y4f = (const float4*)sY;
        #pragma unroll
        for (int q=0; q<16; q++){
          float4 w = wr4[q], y = y4f[q];
          z += w.x*y.x + w.y*y.y + w.z*y.z + w.w*y.w;
        }
        outp[(b*33 + s)*4 + o] = z;
      }
      const uint4* wq = (const uint4*)&sW1h[r*W1STR + m*32 + g*16];
      uint4 W0 = wq[0], W1v = wq[1];
      const uint4* y4 = (const uint4*)sYinp;
      const int qa = m*4 + g*2;               // own quarter: 2 uint4
      uint4 A0 = y4[qa], A1 = y4[qa+1];
      float z0 = dot2(W0.x,  A0.x, 0.f), z1 = dot2(W0.y,  A0.y, 0.f);
      z0 = dot2(W0.z,  A0.z, z0); z1 = dot2(W0.w,  A0.w, z1);
      z0 = dot2(W1v.x, A1.x, z0); z1 = dot2(W1v.y, A1.y, z1);
      z0 = dot2(W1v.z, A1.z, z0); z1 = dot2(W1v.w, A1.w, z1);
      float z = z0 + z1;
      z = dppadd<DPP_XOR1>(z);                // sum m quarters
      z = dppadd<DPP_XOR2>(z);                // sum g quarters
      z += b1r;
      float sg = 1.f/(1.f+__expf(-z));
      if ((t & 3) == 0){
        sH1[r]  = (_Float16)(0.909f*z*sg);
        sDp1[r] = 0.909f*sg*(1.f + z*(1.f-sg));
      }
    }
    __syncthreads();
    // ---- B (MFMA, N=1): h2 = lipswish(W2 h1 + b2); A-frag from LDS ----
    {
      const int w2row = (16*wv + cn)*W2STR;
      f32x4 acc = {0.f, 0.f, 0.f, 0.f};
      #pragma unroll
      for (int c=0; c<4; c++){
        f16x8 af = *(const f16x8*)&sW2h[w2row + 32*c + 8*kg];
        f16x8 bf = {};
        if (cn == 0) bf = *(const f16x8*)&sH1[32*c + kg*8];
        acc = __builtin_amdgcn_mfma_f32_16x16x32_f16(af, bf, acc, 0, 0, 0);
      }
      if (cn == 0){
        #pragma unroll
        for (int j=0; j<4; j++){
          const int row = 16*wv + kg*4 + j;
          float z = acc[j] + sB2[row];
          float sg = 1.f/(1.f+__expf(-z));
          sH2[row]  = (_Float16)(0.909f*z*sg);
          sDp2[row] = 0.909f*sg*(1.f + z*(1.f-sg));
        }
      }
    }
    __syncthreads();
    // ---- C: f = tanh(W3 h2 + b3) -> sFt[a][i]; FUSED wave-local U-fold:
    //      u_j[a] = sum_i C[j,i] f_i[a]; cluster t=8a..8a+7 writes+reads ----
    {
      const uint4* h4 = (const uint4*)sH2;
      float e0=0.f, e1=0.f, o0=0.f, o1=0.f;
      #pragma unroll
      for (int q=0; q<8; q++){
        uint4 hv = h4[(a8&1)*8 + q];          // own K-half only (8 uint4)
        e0 = dot2(w3e[4*q+0], hv.x, e0); e1 = dot2(w3e[4*q+1], hv.y, e1);
        e0 = dot2(w3e[4*q+2], hv.z, e0); e1 = dot2(w3e[4*q+3], hv.w, e1);
        o0 = dot2(w3o[4*q+0], hv.x, o0); o1 = dot2(w3o[4*q+1], hv.y, o1);
        o0 = dot2(w3o[4*q+2], hv.z, o0); o1 = dot2(w3o[4*q+3], hv.w, o1);
      }
      float se = dppadd<DPP_ROR8>(e0+e1);     // + partner's other-half partial
      float so = dppadd<DPP_ROR8>(o0+o1);
      fr = tanh_fast(((a8&1) ? so : se) + b3r);
      sFt[a8*8 + i8] = (_Float16)fr;          // transposed
      asm volatile("s_waitcnt lgkmcnt(0)" ::: "memory");
      uint4 fv = *(const uint4*)&sFt[a8*8];   // f_0..7[a8], same 8-lane group
      h2 f01 = __builtin_bit_cast(h2, fv.x);
      h2 f23 = __builtin_bit_cast(h2, fv.y);
      h2 f45 = __builtin_bit_cast(h2, fv.z);
      h2 f67 = __builtin_bit_cast(h2, fv.w);
      const float4* c4 = (const float4*)sC;
      float4 cA = c4[i8*2], cB = c4[i8*2+1];  // C[j=i8][0..7]
      float u = cA.x*(float)f01[0] + cA.y*(float)f01[1]
              + cA.z*(float)f23[0] + cA.w*(float)f23[1]
              + cB.x*(float)f45[0] + cB.y*(float)f45[1]
              + cB.z*(float)f67[0] + cB.w*(float)f67[1];
      sU[i8*USTR + a8] = (_Float16)u;
    }
    __syncthreads();
    // ---- P (MFMA): D1 = dp1 .* (W1 @ U); A-frag from LDS ----
    {
      const int w1row = (16*wv + cn)*W1STR;
      f32x4 acc = {0.f, 0.f, 0.f, 0.f};
      #pragma unroll
      for (int c=0; c<2; c++){
        f16x8 af = *(const f16x8*)&sW1h[w1row + 32*c + 8*kg];
        f16x8 bf = *(const f16x8*)&sU[cn*USTR + 32*c + kg*8];
        acc = __builtin_amdgcn_mfma_f32_16x16x32_f16(af, bf, acc, 0, 0, 0);
      }
      if (cn < 8){
        #pragma unroll
        for (int j=0; j<4; j++){
          const int row = 16*wv + kg*4 + j;
          sD1[cn*DSTR + row] = (_Float16)(sDp1[row]*acc[j]);
        }
      }
    }
    __syncthreads();
    // ---- E (MFMA): D2 = dp2 .* (W2 @ D1); A-frag from LDS ----
    {
      const int w2row = (16*wv + cn)*W2STR;
      f32x4 acc = {0.f, 0.f, 0.f, 0.f};
      #pragma unroll
      for (int c=0; c<4; c++){
        f16x8 af = *(const f16x8*)&sW2h[w2row + 32*c + 8*kg];
        f16x8 bf = *(const f16x8*)&sD1[cn*DSTR + 32*c + kg*8];
        acc = __builtin_amdgcn_mfma_f32_16x16x32_f16(af, bf, acc, 0, 0, 0);
      }
      if (cn < 8){
        #pragma unroll
        for (int j=0; j<4; j++){
          const int row = 16*wv + kg*4 + j;
          sD2[cn*DSTR + row] = (_Float16)(sDp2[row]*acc[j]);
        }
      }
    }
    __syncthreads();
    // ---- F: con = g_i*f + (1-f^2)*(W3 D2_i); k-sum all-DPP; Heun fused ----
    {
      const uint4* d4 = (const uint4*)&sD2[i8*DSTR];
      float e0=0.f, e1=0.f, o0=0.f, o1=0.f;
      #pragma unroll
      for (int q=0; q<8; q++){
        uint4 dv = d4[(a8&1)*8 + q];          // own K-half of D2[i8]
        e0 = dot2(w3e[4*q+0], dv.x, e0); e1 = dot2(w3e[4*q+1], dv.y, e1);
        e0 = dot2(w3e[4*q+2], dv.z, e0); e1 = dot2(w3e[4*q+3], dv.w, e1);
        o0 = dot2(w3o[4*q+0], dv.x, o0); o1 = dot2(w3o[4*q+1], dv.y, o1);
        o0 = dot2(w3o[4*q+2], dv.z, o0); o1 = dot2(w3o[4*q+3], dv.w, o1);
      }
      float ze = dppadd<DPP_ROR8>(e0+e1);
      float zo = dppadd<DPP_ROR8>(o0+o1);
      float z  = (a8&1) ? zo : ze;
      float con = gi*fr + (1.f - fr*fr)*z;
      con = dppadd<DPP_XOR1>(con);            // i8 bit0
      con = dppadd<DPP_XOR2>(con);            // i8 bit1
      con = dppadd<DPP_HMIR>(con);            // i8 bit2 (quad uniform -> l^7 ok)
      if (i8 == 0){
        if (mode == 0){
          sK1[a8] = con;
          sYinp[a8] = (_Float16)(sY[a8] + con);   // midpoint input for eval2
        } else {
          float yn = sY[a8] + 0.5f*(sK1[a8] + con);
          sY[a8] = yn;
          sYinp[a8] = (_Float16)yn;
        }
      }
    }
  };

  // ---- main scan over windows ----
  for (int s = 0; s < NWIN; s++){
    const float* gcur = &sG[s*LSIG];
    gi = gcur[i8];
    // build antisymmetric C[j][i] in LDS (t<64; R16-proven pattern).
    // Safe: prev EVAL's last sC read (C+U phase) is >=3 barriers old;
    // EVAL(0)'s top __syncthreads publishes before the next read.
    if (t < 64){
      const int j = t >> 3, i = t & 7;
      float v = 0.f;
      if (i < j)      v =  gcur[8 + 7*i - (i*(i-1))/2 + (j-i-1)];
      else if (i > j) v = -gcur[8 + 7*j - (j*(j-1))/2 + (i-j-1)];
      sC[j*8 + i] = v;
    }
    EVAL(0, s);
    EVAL(1, s);
  }
  __syncthreads();
  if (t < 4){                                 // final readout (y after win 31)
    float z = sBr[t] + sSh[0];
    #pragma unroll 8
    for (int a=0; a<64; a++) z += sWr[t*64+a]*sY[a];
    outp[(b*33 + 32)*4 + t] = z;
  }
}

extern "C" void kernel_launch(void* const* d_in, const int* in_sizes, int n_in,
                              void* d_out, int out_size, void* d_ws, size_t ws_size,
                              hipStream_t stream) {
  cde_kernel<<<dim3(NBATCH), dim3(512), 0, stream>>>(
      (const float*)d_in[0],
      (const float*)d_in[1],  (const float*)d_in[2],
      (const float*)d_in[3],  (const float*)d_in[4],
      (const float*)d_in[5],  (const float*)d_in[6],
      (const float*)d_in[7],  (const float*)d_in[8],
      (const float*)d_in[9],  (const float*)d_in[10],
      (const float*)d_in[11], (const float*)d_in[12],
      (const float*)d_in[13],
      (float*)d_out);
}

// Round 13
// 288.240 us; speedup vs baseline: 1.1008x; 1.1008x over previous
//
#include <hip/hip_runtime.h>

// log-ODE Neural CDE. B=32 chains, 32 windows, Heun = 2 vector-field evals
// per window. fp32 in/out, f32 accum, f16 weights/activations.
// 512 threads/block (8 waves), one block per batch element.
//
// R22 = R20 trunk (222.7us best) + MFMA accumulator chain-splitting.
// Post-mortem R21: LDS-staged weights regressed (-20us: +11 b128/lane/eval,
// conflicts 444K->1.23M) and FALSIFIED the weight-word spill theory --
// VGPR=128 / WRITE=713KB are an allocator equilibrium (freed regs get
// re-spent on scheduling), write traffic is init-time, not loop-path.
// Register-resident A-frags are worth their registers. Reverted.
// This round: B and E chain 4 dependent MFMAs, P chains 2. Split each into
// two independent half-chains + vector add (same chain-shortening move that
// won R19->R20 on dot2, applied to the matrix pipe):
//  * B/E: acc0 <- c0,c1 ; acc1 <- c2,c3 ; acc = acc0+acc1.
//  * P: two independent MFMAs + add.
// Phases: A(dot2 quarter) | B-mfma | C+Ufold | P-mfma | E-mfma | F(dot2).
// 6 barriers/eval. Pre-commitment: |delta|<2% => declare latency floor.
#define NBATCH 32
#define LPATH  513
#define NWIN   32
#define LSIG   36
#define DSTR   136   // [dir] stride sD1/sD2 (f16) = 17 uint4
#define USTR   72    // [dir] stride sU (f16) = 9 uint4

typedef unsigned int u32;
typedef _Float16 h2 __attribute__((ext_vector_type(2)));
typedef _Float16 f16x8 __attribute__((ext_vector_type(8)));
typedef float f32x4 __attribute__((ext_vector_type(4)));

__device__ __forceinline__ u32 pkh(float a, float b){
  return __builtin_bit_cast(u32, __builtin_amdgcn_cvt_pkrtz(a, b));
}
__device__ __forceinline__ float dot2(u32 a, u32 b, float c){
#if __has_builtin(__builtin_amdgcn_fdot2)
  return __builtin_amdgcn_fdot2(__builtin_bit_cast(h2,a),
                                __builtin_bit_cast(h2,b), c, false);
#else
  h2 x = __builtin_bit_cast(h2,a), y = __builtin_bit_cast(h2,b);
  return c + (float)x[0]*(float)y[0] + (float)x[1]*(float)y[1];
#endif
}
__device__ __forceinline__ float tanh_fast(float x){
  float e = __expf(2.f*x);
  return 1.f - 2.f/(e+1.f);
}

// DPP cross-lane adds: VALU-only, no LDS-pipe traffic.
#define DPP_XOR1 0xB1   // quad_perm [1,0,3,2]
#define DPP_XOR2 0x4E   // quad_perm [2,3,0,1]
#define DPP_ROR8 0x128  // row_ror:8 == lane^8 within each 16-lane row
#define DPP_HMIR 0x141  // row_half_mirror == lane^7 within each 8-lane half
template<int CTRL>
__device__ __forceinline__ float dppadd(float x){
  int v = __builtin_amdgcn_update_dpp(0, __builtin_bit_cast(int,x),
                                      CTRL, 0xF, 0xF, false);
  return x + __builtin_bit_cast(float, v);
}

extern "C" __global__ __launch_bounds__(512, 1)
void cde_kernel(const float* __restrict__ cv,
                const float* __restrict__ Wi1g, const float* __restrict__ bi1g,
                const float* __restrict__ Wi2g, const float* __restrict__ bi2g,
                const float* __restrict__ W1g,  const float* __restrict__ b1g,
                const float* __restrict__ W2g,  const float* __restrict__ b2g,
                const float* __restrict__ W3g,  const float* __restrict__ b3g,
                const float* __restrict__ Wrg,  const float* __restrict__ brg,
                const float* __restrict__ shg,
                float* __restrict__ outp)
{
  // ---- LDS (~18.5 KB) ----
  __shared__ __align__(16) float sG[NWIN*LSIG];
  __shared__ __align__(16) float sWr[256];
  __shared__ float sBr[4], sSh[1];
  __shared__ __align__(16) float sY[64];
  __shared__ float sK1[64], sLw[64];
  __shared__ __align__(16) float sC[64];       // C[j][i] per window
  __shared__ float sB2[128];                   // b2 (B-MFMA rows != t-row)
  __shared__ float sDp1[128], sDp2[128];       // lipswish derivs (A->P, B->E)
  __shared__ __align__(16) _Float16 sYinp[64];
  __shared__ __align__(16) _Float16 sH1[128];
  __shared__ __align__(16) _Float16 sH2[128];
  __shared__ __align__(16) _Float16 sFt[64*8];     // f transposed: [a][i]
  __shared__ __align__(16) _Float16 sU [16*USTR];  // u[j][a], dirs 8-15 zero
  __shared__ __align__(16) _Float16 sD1[16*DSTR];  // dirs 8-15 zero-padded
  __shared__ __align__(16) _Float16 sD2[8*DSTR];

  const int t  = threadIdx.x;        // 0..511
  const int b  = blockIdx.x;
  const int wv = t >> 6;             // wave id 0..7 (MFMA M-tile)
  const int l  = t & 63;             // lane id
  const int cn = l & 15;             // MFMA N-lane (col)
  const int kg = l >> 4;             // MFMA K-group
  const int r  = t >> 2;             // 0..127 (A row)
  const int m  = t & 1;              // A quarter bit 0
  const int g  = (t >> 1) & 1;       // A quarter bit 1
  const int i8 = t & 7;              // dir (C/F row-block; U-fold j)
  const int a8 = t >> 3;             // 0..63 (C/F col; U-fold elem)
  const int p  = i8*64 + a8;         // owned W3 row
  const int pE = i8*64 + (a8 & ~1);  // C/F pair's even row
  const int pO = i8*64 + (a8 |  1);  // C/F pair's odd row

  // ---- init consts + zero-pad sU / sD1 dirs 8-15 (stay zero forever) ----
  if (t < 256) sWr[t] = Wrg[t];
  if (t < 4)   sBr[t] = brg[t];
  if (t == 0)  sSh[0] = shg[0];
  if (t < 128) sB2[t] = b2g[t];
  for (int z = t; z < 8*DSTR; z += 512) sD1[8*DSTR + z] = (_Float16)0.f;
  for (int z = t; z < 8*USTR; z += 512) sU[8*USTR + z] = (_Float16)0.f;

  // ---- depth-2 Lyndon log-signatures, one window per thread (t<32) ----
  if (t < NWIN){
    const float4* cv4 = (const float4*)cv;
    const int base = (b*LPATH + t*16)*2;
    float cur[8], pre[8], acc[8], lvw[28];
    { float4 a = cv4[base], d = cv4[base+1];
      cur[0]=a.x;cur[1]=a.y;cur[2]=a.z;cur[3]=a.w;
      cur[4]=d.x;cur[5]=d.y;cur[6]=d.z;cur[7]=d.w; }
    #pragma unroll
    for (int d=0; d<8; d++){ pre[d]=0.f; acc[d]=0.f; }
    #pragma unroll
    for (int pq=0; pq<28; pq++) lvw[pq]=0.f;
    for (int w=1; w<=16; w++){
      float nxt[8], inc[8];
      { float4 a = cv4[base+2*w], d = cv4[base+2*w+1];
        nxt[0]=a.x;nxt[1]=a.y;nxt[2]=a.z;nxt[3]=a.w;
        nxt[4]=d.x;nxt[5]=d.y;nxt[6]=d.z;nxt[7]=d.w; }
      #pragma unroll
      for (int d=0; d<8; d++) inc[d] = nxt[d]-cur[d];
      int pq=0;
      #pragma unroll
      for (int i=0; i<8; i++)
        #pragma unroll
        for (int j2=i+1; j2<8; j2++){ lvw[pq] += pre[i]*inc[j2] - pre[j2]*inc[i]; pq++; }
      #pragma unroll
      for (int d=0; d<8; d++){ acc[d]+=inc[d]; pre[d]+=inc[d]; cur[d]=nxt[d]; }
    }
    float* gd = &sG[t*LSIG];
    #pragma unroll
    for (int d=0; d<8; d++) gd[d] = acc[d];
    #pragma unroll
    for (int pq=0; pq<28; pq++) gd[8+pq] = 0.5f*lvw[pq];
  }

  // ---- y0 = Wi2 @ lipswish(Wi1 @ x0 + bi1) + bi2 ----
  if (t < 64){
    float z = bi1g[t];
    #pragma unroll
    for (int d=0; d<8; d++) z += Wi1g[t*8+d] * cv[(b*LPATH)*8 + d];
    float s = 1.f/(1.f+__expf(-z));
    sLw[t] = 0.909f*z*s;
  }
  __syncthreads();
  if (t < 64){
    float z = bi2g[t];
    #pragma unroll 8
    for (int k=0; k<64; k++) z += Wi2g[t*64+k] * sLw[k];
    sY[t] = z;
    sYinp[t] = (_Float16)z;
  }
  __syncthreads();
  if (t < 4){
    float z = sBr[t] + sSh[0];
    #pragma unroll 8
    for (int a=0; a<64; a++) z += sWr[t*64+a]*sY[a];
    outp[(b*33 + 0)*4 + t] = z;
  }

  // ---- per-thread weight registers ----
  // w1A: (m,g)-quarter (16 cols) of W1 row r          -> A (R16-proven).
  // w1f: MFMA A-frag W1[16wv+cn][32c+kg*8+e], c=0,1   -> P phase.
  // w2f: MFMA A-frag W2[16wv+cn][32c+kg*8+e], c=0..3  -> B and E phases.
  // w3e/w3o: K-half (a8&1) of rows pE/pO              -> C and F (dot2).
  u32 w1A[8], w3e[32], w3o[32];
  f16x8 w1f[2], w2f[4];
  {
    const float2* W1f2 = (const float2*)W1g;
    #pragma unroll
    for (int i=0; i<8; i++){ float2 v = W1f2[r*32 + m*16 + g*8 + i]; w1A[i] = pkh(v.x, v.y); }
    #pragma unroll
    for (int c=0; c<2; c++){
      uint4 tv;
      float2 v0 = W1f2[(16*wv + cn)*32 + 16*c + kg*4 + 0];
      float2 v1 = W1f2[(16*wv + cn)*32 + 16*c + kg*4 + 1];
      float2 v2 = W1f2[(16*wv + cn)*32 + 16*c + kg*4 + 2];
      float2 v3 = W1f2[(16*wv + cn)*32 + 16*c + kg*4 + 3];
      tv.x = pkh(v0.x, v0.y); tv.y = pkh(v1.x, v1.y);
      tv.z = pkh(v2.x, v2.y); tv.w = pkh(v3.x, v3.y);
      w1f[c] = __builtin_bit_cast(f16x8, tv);
    }
    const float2* W2f2 = (const float2*)W2g;
    #pragma unroll
    for (int c=0; c<4; c++){
      uint4 tv;
      float2 v0 = W2f2[(16*wv + cn)*64 + 16*c + kg*4 + 0];
      float2 v1 = W2f2[(16*wv + cn)*64 + 16*c + kg*4 + 1];
      float2 v2 = W2f2[(16*wv + cn)*64 + 16*c + kg*4 + 2];
      float2 v3 = W2f2[(16*wv + cn)*64 + 16*c + kg*4 + 3];
      tv.x = pkh(v0.x, v0.y); tv.y = pkh(v1.x, v1.y);
      tv.z = pkh(v2.x, v2.y); tv.w = pkh(v3.x, v3.y);
      w2f[c] = __builtin_bit_cast(f16x8, tv);
    }
    const float4* W3f4 = (const float4*)W3g;
    #pragma unroll
    for (int k=0; k<16; k++){
      float4 v = W3f4[pE*32 + (a8&1)*16 + k];
      w3e[2*k]   = pkh(v.x, v.y);
      w3e[2*k+1] = pkh(v.z, v.w);
    }
    #pragma unroll
    for (int k=0; k<16; k++){
      float4 v = W3f4[pO*32 + (a8&1)*16 + k];
      w3o[2*k]   = pkh(v.x, v.y);
      w3o[2*k+1] = pkh(v.z, v.w);
    }
  }
  const float b1r = b1g[r], b3r = b3g[p];

  float gi = 0.f;       // gcur[i8], per window

  // One vector-field eval. mode 0: k1 (sK1, sYinp=y+k1, fused readout in A).
  // mode 1: k2 (Heun update fused in F).
  auto EVAL = [&](int mode, int s){
    __syncthreads();                          // sYinp (and sY, sC) ready
    float fr;
    // ---- A: h1 = lipswish(W1 y + b1); (m,g) quarter split (R16) ----
    {
      if (mode == 0 && s > 0 && t >= 504 && t < 508){
        int o = t - 504;
        float z = sBr[o] + sSh[0];
        const float4* wr4 = (const float4*)&sWr[o*64];
        const float4* y4f = (const float4*)sY;
        #pragma unroll
        for (int q=0; q<16; q++){
          float4 w = wr4[q], y = y4f[q];
          z += w.x*y.x + w.y*y.y + w.z*y.z + w.w*y.w;
        }
        outp[(b*33 + s)*4 + o] = z;
      }
      const uint4* y4 = (const uint4*)sYinp;
      const int qa = m*4 + g*2;               // own quarter: 2 uint4
      uint4 A0 = y4[qa], A1 = y4[qa+1];
      float z0 = dot2(w1A[0], A0.x, 0.f), z1 = dot2(w1A[1], A0.y, 0.f);
      z0 = dot2(w1A[2], A0.z, z0); z1 = dot2(w1A[3], A0.w, z1);
      z0 = dot2(w1A[4], A1.x, z0); z1 = dot2(w1A[5], A1.y, z1);
      z0 = dot2(w1A[6], A1.z, z0); z1 = dot2(w1A[7], A1.w, z1);
      float z = z0 + z1;
      z = dppadd<DPP_XOR1>(z);                // sum m quarters
      z = dppadd<DPP_XOR2>(z);                // sum g quarters
      z += b1r;
      float sg = 1.f/(1.f+__expf(-z));
      if ((t & 3) == 0){
        sH1[r]  = (_Float16)(0.909f*z*sg);
        sDp1[r] = 0.909f*sg*(1.f + z*(1.f-sg));
      }
    }
    __syncthreads();
    // ---- B (MFMA, N=1): h2 = lipswish(W2 h1 + b2); split 2+2 chains ----
    {
      f32x4 acc0 = {0.f, 0.f, 0.f, 0.f};
      f32x4 acc1 = {0.f, 0.f, 0.f, 0.f};
      f16x8 bf0 = {}, bf1 = {}, bf2 = {}, bf3 = {};
      if (cn == 0){
        bf0 = *(const f16x8*)&sH1[ 0 + kg*8];
        bf1 = *(const f16x8*)&sH1[32 + kg*8];
        bf2 = *(const f16x8*)&sH1[64 + kg*8];
        bf3 = *(const f16x8*)&sH1[96 + kg*8];
      }
      acc0 = __builtin_amdgcn_mfma_f32_16x16x32_f16(w2f[0], bf0, acc0, 0, 0, 0);
      acc1 = __builtin_amdgcn_mfma_f32_16x16x32_f16(w2f[2], bf2, acc1, 0, 0, 0);
      acc0 = __builtin_amdgcn_mfma_f32_16x16x32_f16(w2f[1], bf1, acc0, 0, 0, 0);
      acc1 = __builtin_amdgcn_mfma_f32_16x16x32_f16(w2f[3], bf3, acc1, 0, 0, 0);
      f32x4 acc = acc0 + acc1;
      if (cn == 0){
        #pragma unroll
        for (int j=0; j<4; j++){
          const int row = 16*wv + kg*4 + j;
          float z = acc[j] + sB2[row];
          float sg = 1.f/(1.f+__expf(-z));
          sH2[row]  = (_Float16)(0.909f*z*sg);
          sDp2[row] = 0.909f*sg*(1.f + z*(1.f-sg));
        }
      }
    }
    __syncthreads();
    // ---- C: f = tanh(W3 h2 + b3) -> sFt[a][i]; FUSED wave-local U-fold:
    //      u_j[a] = sum_i C[j,i] f_i[a]; cluster t=8a..8a+7 writes+reads ----
    {
      const uint4* h4 = (const uint4*)sH2;
      float e0=0.f, e1=0.f, o0=0.f, o1=0.f;
      #pragma unroll
      for (int q=0; q<8; q++){
        uint4 hv = h4[(a8&1)*8 + q];          // own K-half only (8 uint4)
        e0 = dot2(w3e[4*q+0], hv.x, e0); e1 = dot2(w3e[4*q+1], hv.y, e1);
        e0 = dot2(w3e[4*q+2], hv.z, e0); e1 = dot2(w3e[4*q+3], hv.w, e1);
        o0 = dot2(w3o[4*q+0], hv.x, o0); o1 = dot2(w3o[4*q+1], hv.y, o1);
        o0 = dot2(w3o[4*q+2], hv.z, o0); o1 = dot2(w3o[4*q+3], hv.w, o1);
      }
      float se = dppadd<DPP_ROR8>(e0+e1);     // + partner's other-half partial
      float so = dppadd<DPP_ROR8>(o0+o1);
      fr = tanh_fast(((a8&1) ? so : se) + b3r);
      sFt[a8*8 + i8] = (_Float16)fr;          // transposed
      asm volatile("s_waitcnt lgkmcnt(0)" ::: "memory");
      uint4 fv = *(const uint4*)&sFt[a8*8];   // f_0..7[a8], same 8-lane group
      h2 f01 = __builtin_bit_cast(h2, fv.x);
      h2 f23 = __builtin_bit_cast(h2, fv.y);
      h2 f45 = __builtin_bit_cast(h2, fv.z);
      h2 f67 = __builtin_bit_cast(h2, fv.w);
      const float4* c4 = (const float4*)sC;
      float4 cA = c4[i8*2], cB = c4[i8*2+1];  // C[j=i8][0..7]
      float u = cA.x*(float)f01[0] + cA.y*(float)f01[1]
              + cA.z*(float)f23[0] + cA.w*(float)f23[1]
              + cB.x*(float)f45[0] + cB.y*(float)f45[1]
              + cB.z*(float)f67[0] + cB.w*(float)f67[1];
      sU[i8*USTR + a8] = (_Float16)u;
    }
    __syncthreads();
    // ---- P (MFMA): D1 = dp1 .* (W1 @ U); two independent MFMAs + add ----
    {
      f32x4 z4 = {0.f, 0.f, 0.f, 0.f};
      f16x8 bf0 = *(const f16x8*)&sU[cn*USTR +  0 + kg*8];
      f16x8 bf1 = *(const f16x8*)&sU[cn*USTR + 32 + kg*8];
      f32x4 acc0 = __builtin_amdgcn_mfma_f32_16x16x32_f16(w1f[0], bf0, z4, 0, 0, 0);
      f32x4 acc1 = __builtin_amdgcn_mfma_f32_16x16x32_f16(w1f[1], bf1, z4, 0, 0, 0);
      f32x4 acc = acc0 + acc1;
      if (cn < 8){
        #pragma unroll
        for (int j=0; j<4; j++){
          const int row = 16*wv + kg*4 + j;
          sD1[cn*DSTR + row] = (_Float16)(sDp1[row]*acc[j]);
        }
      }
    }
    __syncthreads();
    // ---- E (MFMA): D2 = dp2 .* (W2 @ D1); split 2+2 chains ----
    {
      f32x4 acc0 = {0.f, 0.f, 0.f, 0.f};
      f32x4 acc1 = {0.f, 0.f, 0.f, 0.f};
      f16x8 bf0 = *(const f16x8*)&sD1[cn*DSTR +  0 + kg*8];
      f16x8 bf1 = *(const f16x8*)&sD1[cn*DSTR + 32 + kg*8];
      f16x8 bf2 = *(const f16x8*)&sD1[cn*DSTR + 64 + kg*8];
      f16x8 bf3 = *(const f16x8*)&sD1[cn*DSTR + 96 + kg*8];
      acc0 = __builtin_amdgcn_mfma_f32_16x16x32_f16(w2f[0], bf0, acc0, 0, 0, 0);
      acc1 = __builtin_amdgcn_mfma_f32_16x16x32_f16(w2f[2], bf2, acc1, 0, 0, 0);
      acc0 = __builtin_amdgcn_mfma_f32_16x16x32_f16(w2f[1], bf1, acc0, 0, 0, 0);
      acc1 = __builtin_amdgcn_mfma_f32_16x16x32_f16(w2f[3], bf3, acc1, 0, 0, 0);
      f32x4 acc = acc0 + acc1;
      if (cn < 8){
        #pragma unroll
        for (int j=0; j<4; j++){
          const int row = 16*wv + kg*4 + j;
          sD2[cn*DSTR + row] = (_Float16)(sDp2[row]*acc[j]);
        }
      }
    }
    __syncthreads();
    // ---- F: con = g_i*f + (1-f^2)*(W3 D2_i); k-sum all-DPP; Heun fused ----
    {
      const uint4* d4 = (const uint4*)&sD2[i8*DSTR];
      float e0=0.f, e1=0.f, o0=0.f, o1=0.f;
      #pragma unroll
      for (int q=0; q<8; q++){
        uint4 dv = d4[(a8&1)*8 + q];          // own K-half of D2[i8]
        e0 = dot2(w3e[4*q+0], dv.x, e0); e1 = dot2(w3e[4*q+1], dv.y, e1);
        e0 = dot2(w3e[4*q+2], dv.z, e0); e1 = dot2(w3e[4*q+3], dv.w, e1);
        o0 = dot2(w3o[4*q+0], dv.x, o0); o1 = dot2(w3o[4*q+1], dv.y, o1);
        o0 = dot2(w3o[4*q+2], dv.z, o0); o1 = dot2(w3o[4*q+3], dv.w, o1);
      }
      float ze = dppadd<DPP_ROR8>(e0+e1);
      float zo = dppadd<DPP_ROR8>(o0+o1);
      float z  = (a8&1) ? zo : ze;
      float con = gi*fr + (1.f - fr*fr)*z;
      con = dppadd<DPP_XOR1>(con);            // i8 bit0
      con = dppadd<DPP_XOR2>(con);            // i8 bit1
      con = dppadd<DPP_HMIR>(con);            // i8 bit2 (quad uniform -> l^7 ok)
      if (i8 == 0){
        if (mode == 0){
          sK1[a8] = con;
          sYinp[a8] = (_Float16)(sY[a8] + con);   // midpoint input for eval2
        } else {
          float yn = sY[a8] + 0.5f*(sK1[a8] + con);
          sY[a8] = yn;
          sYinp[a8] = (_Float16)yn;
        }
      }
    }
  };

  // ---- main scan over windows ----
  for (int s = 0; s < NWIN; s++){
    const float* gcur = &sG[s*LSIG];
    gi = gcur[i8];
    // build antisymmetric C[j][i] in LDS (t<64; R16-proven pattern).
    // Safe: prev EVAL's last sC read (C+U phase) is >=3 barriers old;
    // EVAL(0)'s top __syncthreads publishes before the next read.
    if (t < 64){
      const int j = t >> 3, i = t & 7;
      float v = 0.f;
      if (i < j)      v =  gcur[8 + 7*i - (i*(i-1))/2 + (j-i-1)];
      else if (i > j) v = -gcur[8 + 7*j - (j*(j-1))/2 + (i-j-1)];
      sC[j*8 + i] = v;
    }
    EVAL(0, s);
    EVAL(1, s);
  }
  __syncthreads();
  if (t < 4){                                 // final readout (y after win 31)
    float z = sBr[t] + sSh[0];
    #pragma unroll 8
    for (int a=0; a<64; a++) z += sWr[t*64+a]*sY[a];
    outp[(b*33 + 32)*4 + t] = z;
  }
}

extern "C" void kernel_launch(void* const* d_in, const int* in_sizes, int n_in,
                              void* d_out, int out_size, void* d_ws, size_t ws_size,
                              hipStream_t stream) {
  cde_kernel<<<dim3(NBATCH), dim3(512), 0, stream>>>(
      (const float*)d_in[0],
      (const float*)d_in[1],  (const float*)d_in[2],
      (const float*)d_in[3],  (const float*)d_in[4],
      (const float*)d_in[5],  (const float*)d_in[6],
      (const float*)d_in[7],  (const float*)d_in[8],
      (const float*)d_in[9],  (const float*)d_in[10],
      (const float*)d_in[11], (const float*)d_in[12],
      (const float*)d_in[13],
      (float*)d_out);
}